// Round 1
// baseline (456.838 us; speedup 1.0000x reference)
//
#include <hip/hip_runtime.h>
#include <cstdint>

typedef unsigned short u16;
typedef unsigned int   u32;
typedef unsigned long long u64;

#define G_ROWS 20000
#define G_PAD  20096      // 157 * 128 (conv padding; gemm over-reads past this, guarded on store)
#define T_DIM  1536
#define D_DIM  512
#define B_DIM  256
#define TOPK   32
#define SIM_SCALE 0.04419417382415922f   // 1/sqrt(512), screening only
#define SQRT_D    22.62741699796952f     // f32(math.sqrt(512)) — np divides by this
#define BOUND_EPS 2.0e-4f                // per-element screen-vs-np error bound (true ~5e-6; 40x margin)

typedef __bf16 bf16x8 __attribute__((ext_vector_type(8)));
typedef float  f32x4  __attribute__((ext_vector_type(4)));

__device__ __forceinline__ u16 f2bf(float f) {
  u32 u = __float_as_uint(f);
  u += 0x7fffu + ((u >> 16) & 1u);   // RNE
  return (u16)(u >> 16);
}
__device__ __forceinline__ float bf2f(u16 h) {
  return __uint_as_float(((u32)h) << 16);
}
__device__ __forceinline__ u32 fkey(float v) {   // order-preserving f32 -> u32
  u32 b = __float_as_uint(v);
  return (b & 0x80000000u) ? ~b : (b | 0x80000000u);
}
__device__ __forceinline__ float funkey(u32 o) {
  u32 b = (o & 0x80000000u) ? (o & 0x7FFFFFFFu) : ~o;
  return __uint_as_float(b);
}

// ---------------- split-conversion: f32 -> (bf16 hi, bf16 lo) ----------------
__global__ __launch_bounds__(256) void conv_split(const float* __restrict__ src,
                                                  u16* __restrict__ hi, u16* __restrict__ lo,
                                                  int valid_rows)
{
  size_t i = ((size_t)blockIdx.x * 256 + threadIdx.x) * 4;
  int row = (int)(i >> 9);
  float4 a = make_float4(0.f, 0.f, 0.f, 0.f);
  if (row < valid_rows) a = *(const float4*)(src + i);
  float v[4] = {a.x, a.y, a.z, a.w};
  u16 h[4], l[4];
#pragma unroll
  for (int c = 0; c < 4; ++c) {
    h[c] = f2bf(v[c]);
    l[c] = f2bf(v[c] - bf2f(h[c]));
  }
  *(uint2*)(hi + i) = make_uint2((u32)h[0] | ((u32)h[1] << 16), (u32)h[2] | ((u32)h[3] << 16));
  *(uint2*)(lo + i) = make_uint2((u32)l[0] | ((u32)l[1] << 16), (u32)l[2] | ((u32)l[3] << 16));
}

// ---------------- tf_expr [B,T] -> tfT [T,B] ----------------
__global__ __launch_bounds__(256) void transpose_tf(const float* __restrict__ in, float* __restrict__ out)
{
  __shared__ float tile[32][33];
  int x = threadIdx.x, y = threadIdx.y;
  int bt = blockIdx.x * 32;
  int bb = blockIdx.y * 32;
#pragma unroll
  for (int i = 0; i < 32; i += 8) tile[y + i][x] = in[(size_t)(bb + y + i) * T_DIM + bt + x];
  __syncthreads();
#pragma unroll
  for (int i = 0; i < 32; i += 8) out[(size_t)(bt + y + i) * B_DIM + bb + x] = tile[x][y + i];
}

// ---------------- async global -> LDS, 16B/lane ----------------
__device__ __forceinline__ void gl16(const u16* g, u16* l) {
  __builtin_amdgcn_global_load_lds((__attribute__((address_space(1))) void*)(void*)g,
                                   (__attribute__((address_space(3))) void*)l, 16, 0, 0);
}

// ---------------- screening GEMM: C ~= (Ah+Al)(Bh+Bl)^T via 3 bf16 MFMA terms ----------------
// 256x128 tile, 8 waves, BK=32, double-buffered LDS, counted vmcnt (never 0 in loop),
// conflict-free subtiled LDS layout (chunk = kgroup*16 + row; read addr = base + lane*16),
// bijective XCD swizzle, setprio around MFMA cluster.
#define BMT 256
#define BNT 128
#define NBX 12            // 1536 / 128
#define NWG 948           // 79 * 12  (79 row-panels of 256; last over-reads 128 garbage rows in-workspace)
#define LDS_HALF 24576    // u16 per buffer: Ah 8192 | Al 8192 | Bh 4096 | Bl 4096  (48 KB)

__global__ __launch_bounds__(512, 2) void gemm_split(const u16* __restrict__ Ah, const u16* __restrict__ Al,
                                                     const u16* __restrict__ Bh, const u16* __restrict__ Bl,
                                                     float* __restrict__ Sim)
{
  __shared__ u16 sm[2 * LDS_HALF];   // 96 KB

  // bijective XCD swizzle (m204 variant; NWG % 8 == 4): consecutive wgid on one XCD
  // iterate bx fastest -> the 12 column-blocks of an A row-panel share that XCD's L2.
  const int orig = blockIdx.x;
  const int xcd  = orig & 7;
  const int q    = NWG >> 3, r = NWG & 7;
  const int wgid = (xcd < r ? xcd * (q + 1) : r * (q + 1) + (xcd - r) * q) + (orig >> 3);
  const int by   = wgid / NBX;
  const int bx   = wgid - by * NBX;
  const int bm0  = by * BMT;
  const int bn0  = bx * BNT;

  const int tid  = threadIdx.x;
  const int lane = tid & 63;
  const int wv   = tid >> 6;      // 0..7
  const int wm   = wv >> 1;       // 0..3 : wave row  (64-row strip)
  const int wn   = wv & 1;        // 0..1 : wave col  (64-col strip)

  // staging lane roles: row = lane&15 within the wave's 16-row subtile, kgroup = lane>>4.
  // LDS dest is linear (base + lane*16B) so chunk index == (kgroup*16 + row) == lane.
  const size_t aOff = (size_t)(bm0 + (wv << 4) + (lane & 15)) * 512 + ((lane >> 4) << 3);
  const size_t bOff = (size_t)(bn0 + (wv << 4) + (lane & 15)) * 512 + ((lane >> 4) << 3);

  f32x4 zero4 = {0.f, 0.f, 0.f, 0.f};
  f32x4 acc[4][4];
#pragma unroll
  for (int i = 0; i < 4; ++i)
#pragma unroll
    for (int j = 0; j < 4; ++j) acc[i][j] = zero4;

#define STAGE(pb, kt) do {                                         \
    u16* d = sm + (pb) * LDS_HALF + ((wv) << 9);                   \
    const int k0s = (kt) << 5;                                     \
    gl16(Ah + aOff + k0s,         d);                              \
    gl16(Ah + aOff + k0s + 65536, d + 4096);                       \
    gl16(Al + aOff + k0s,         d + 8192);                       \
    gl16(Al + aOff + k0s + 65536, d + 12288);                      \
    gl16(Bh + bOff + k0s,         d + 16384);                      \
    gl16(Bl + bOff + k0s,         d + 20480);                      \
  } while (0)

  STAGE(0, 0);

#pragma unroll
  for (int kt = 0; kt < 16; ++kt) {
    const int pb = kt & 1;
    if (kt < 15) {
      STAGE(pb ^ 1, kt + 1);                                 // 6 fresh in-flight loads
      asm volatile("s_waitcnt vmcnt(6)" ::: "memory");       // kt's 6 loads have landed
    } else {
      asm volatile("s_waitcnt vmcnt(0)" ::: "memory");       // final tile: drain
    }
    __builtin_amdgcn_s_barrier();                            // raw barrier: no vmcnt(0) drain
    __builtin_amdgcn_sched_barrier(0);                       // pin: no ds_read hoisted above

    const u16* rb = sm + pb * LDS_HALF;
    const int la8 = lane << 3;
    bf16x8 aH[4], aL[4], bH[4], bL[4];
#pragma unroll
    for (int i = 0; i < 4; ++i) {
      const int sa = ((wm << 2) + i) << 9;
      const int sb = ((wn << 2) + i) << 9;
      aH[i] = *(const bf16x8*)(rb + sa + la8);
      aL[i] = *(const bf16x8*)(rb + 8192 + sa + la8);
      bH[i] = *(const bf16x8*)(rb + 16384 + sb + la8);
      bL[i] = *(const bf16x8*)(rb + 20480 + sb + la8);
    }
    __builtin_amdgcn_s_setprio(1);
#pragma unroll
    for (int mi = 0; mi < 4; ++mi)
#pragma unroll
      for (int ni = 0; ni < 4; ++ni) {
        acc[mi][ni] = __builtin_amdgcn_mfma_f32_16x16x32_bf16(aH[mi], bH[ni], acc[mi][ni], 0, 0, 0);
        acc[mi][ni] = __builtin_amdgcn_mfma_f32_16x16x32_bf16(aH[mi], bL[ni], acc[mi][ni], 0, 0, 0);
        acc[mi][ni] = __builtin_amdgcn_mfma_f32_16x16x32_bf16(aL[mi], bH[ni], acc[mi][ni], 0, 0, 0);
      }
    __builtin_amdgcn_s_setprio(0);
    __builtin_amdgcn_sched_barrier(0);                       // pin: nothing from next iter crosses
    __builtin_amdgcn_s_barrier();                            // reads done before next STAGE lands
  }
#undef STAGE

  const int erow0 = bm0 + (wm << 6) + ((lane >> 4) << 2);
  const int ecol0 = bn0 + (wn << 6) + (lane & 15);
#pragma unroll
  for (int mi = 0; mi < 4; ++mi)
#pragma unroll
    for (int rr = 0; rr < 4; ++rr) {
      int row = erow0 + mi * 16 + rr;
      if (row < G_ROWS) {
#pragma unroll
        for (int ni = 0; ni < 4; ++ni)
          Sim[(size_t)row * T_DIM + ecol0 + ni * 16] = acc[mi][ni][rr] * SIM_SCALE;
      }
    }
}

// ---------------- helpers ----------------
__device__ __forceinline__ int count_ge(const float* v, float tau) {
  int c = 0;
#pragma unroll
  for (int j = 0; j < 24; ++j) c += (int)__popcll(__ballot(v[j] >= tau));
  return c;
}
// full 64-lane bitonic sort, descending by u64 key; returns this lane's sorted key
__device__ __forceinline__ u64 bitonic64_desc(u64 key, int lane) {
#pragma unroll
  for (int k = 2; k <= 64; k <<= 1) {
#pragma unroll
    for (int j = k >> 1; j > 0; j >>= 1) {
      u64 p = __shfl_xor(key, j, 64);
      bool lower = (lane & j) == 0;
      bool asc   = (lane & k) != 0;
      u64 mn = (key < p) ? key : p;
      u64 mx = (key < p) ? p : key;
      key = (lower == asc) ? mn : mx;
    }
  }
  return key;
}

// ---------------- per-row (1 wave/row): 6-threshold ladder select, bitonic rank,
// np-replica ONLY when cut is truly contested, register-direct dense write ----------------
__global__ __launch_bounds__(256) void topk_kernel(float* __restrict__ Sim, const int* __restrict__ mask,
                                                   const float* __restrict__ tg_dec,
                                                   const float* __restrict__ tf_base,
                                                   int* __restrict__ tIdx, float* __restrict__ tW)
{
  __shared__ u32 cval[4][64];
  __shared__ int cidxs[4][64];
  const int lane = threadIdx.x & 63;
  const int wv   = threadIdx.x >> 6;
  const int g    = blockIdx.x * 4 + wv;
  float* row = Sim + (size_t)g * T_DIM;
  const int* mrow = mask + (size_t)g * T_DIM;

  // --- vectorized load of sim + mask; apply mask -> -inf ---
  float v[24];
#pragma unroll
  for (int j = 0; j < 6; ++j) {
    float4 q = *(const float4*)(row + j * 256 + lane * 4);
    int4  mq = *(const int4*)(mrow + j * 256 + lane * 4);
    v[j * 4 + 0] = mq.x ? q.x : -INFINITY;
    v[j * 4 + 1] = mq.y ? q.y : -INFINITY;
    v[j * 4 + 2] = mq.z ? q.z : -INFINITY;
    v[j * 4 + 3] = mq.w ? q.w : -INFINITY;
  }

  // --- parallel 6-threshold ladder count (pure VALU) + valid count ---
  const float TH0 = 1.25f, TH1 = 1.40f, TH2 = 1.55f, TH3 = 1.70f, TH4 = 1.85f, TH5 = 2.00f;
  int n0 = 0, n1 = 0, n2 = 0, n3 = 0, n4 = 0, n5 = 0, nv = 0;
#pragma unroll
  for (int j = 0; j < 24; ++j) {
    float x = v[j];
    n0 += (x >= TH0); n1 += (x >= TH1); n2 += (x >= TH2);
    n3 += (x >= TH3); n4 += (x >= TH4); n5 += (x >= TH5);
    nv += (x != -INFINITY);
  }
  // pack 16-bit fields into two u64s, one shfl-reduce pass
  u64 p0 = (u64)(u32)n0 | ((u64)(u32)n1 << 16) | ((u64)(u32)n2 << 32) | ((u64)(u32)n3 << 48);
  u64 p1 = (u64)(u32)n4 | ((u64)(u32)n5 << 16) | ((u64)(u32)nv << 32);
#pragma unroll
  for (int off = 32; off > 0; off >>= 1) {
    p0 += __shfl_xor(p0, off, 64);
    p1 += __shfl_xor(p1, off, 64);
  }
  int c[6];
  c[0] = (int)(p0 & 0xFFFF); c[1] = (int)((p0 >> 16) & 0xFFFF);
  c[2] = (int)((p0 >> 32) & 0xFFFF); c[3] = (int)((p0 >> 48) & 0xFFFF);
  c[4] = (int)(p1 & 0xFFFF); c[5] = (int)((p1 >> 16) & 0xFFFF);
  const int cvalid = (int)((p1 >> 32) & 0xFFFF);

  // --- pick largest threshold with count >= 33; fallback bisect for gaps/extremes (~1%) ---
  float tau; int cnt;
  if (cvalid <= 64) { tau = -3.0e38f; cnt = cvalid; }
  else {
    int is = -1;
#pragma unroll
    for (int i = 0; i < 6; ++i) if (c[i] >= 33) is = i;
    const float THv[7] = {TH0, TH1, TH2, TH3, TH4, TH5, 8.0f};
    if (is >= 0 && c[is] <= 64) { tau = THv[is]; cnt = c[is]; }
    else {
      float lo, hi;
      if (is < 0) { lo = -4.0f; hi = TH0; }         // even TH0 keeps <33 (tiny-scale row)
      else        { lo = THv[is]; hi = THv[is + 1]; } // gap: count(lo)>64, count(hi)<33
      tau = lo; cnt = 1000;
      for (int it = 0; it < 16; ++it) {
        float mid = 0.5f * (lo + hi);
        int cm = count_ge(v, mid);
        if (cm > 64)      lo = mid;
        else if (cm < 33) hi = mid;
        else { tau = mid; cnt = cm; break; }
      }
      if (cnt == 1000) tau = lo;                    // exact-tie pathology; compaction clamps
    }
  }

  // --- ballot-prefix compaction into wave-private LDS ---
  int base = 0;
#pragma unroll
  for (int j = 0; j < 24; ++j) {
    bool pred = (v[j] >= tau);
    u64 bmc = __ballot(pred);
    int pos = base + (int)__popcll(bmc & ((1ull << lane) - 1ull));
    int idx = (j >> 2) * 256 + lane * 4 + (j & 3);
    if (pred && pos < 64) { cval[wv][pos] = fkey(v[j]); cidxs[wv][pos] = idx; }
    base += (int)__popcll(bmc);
  }
  const int cnt_eff = (base < 64) ? base : 64;

  u64 key = 0;
  if (lane < cnt_eff)
    key = ((u64)cval[wv][lane] << 32) | (u64)(u32)(~(u32)cidxs[wv][lane]);

  // --- bitonic sort: lane L = L-th largest (value desc, idx asc) ---
  key = bitonic64_desc(key, lane);
  int   myidx = (int)(~(u32)key);
  float myv   = (key != 0) ? funkey((u32)(key >> 32)) : -INFINITY;

  // --- np-replica ONLY if the 31/32 cut is truly contested: v31 - v32 < 2*eps ---
  float v31 = __shfl(myv, 31, 64);
  float v32 = __shfl(myv, 32, 64);
  if (cnt_eff > TOPK && (v31 - v32) < 2.0f * BOUND_EPS) {
    bool flag = (lane < cnt_eff) &&
                (myv >= v32 - 2.0f * BOUND_EPS) && (myv <= v31 + 2.0f * BOUND_EPS);
    if (flag) {
      // bit-exact np replica: OpenBLAS sgemm sequential-K FMA chain, kc split 384|128,
      // then f32 division by f32(sqrt(512)). Requires strict FP (no fast-math).
      const float* arow_g = tg_dec + (size_t)g * D_DIM;
      const float* brow   = tf_base + (size_t)myidx * D_DIM;
      float s1 = 0.f, s2 = 0.f;
#pragma unroll 8
      for (int k = 0; k < 384; k += 4) {
        float4 av = *(const float4*)(arow_g + k);
        float4 bv = *(const float4*)(brow + k);
        s1 = fmaf(av.x, bv.x, s1); s1 = fmaf(av.y, bv.y, s1);
        s1 = fmaf(av.z, bv.z, s1); s1 = fmaf(av.w, bv.w, s1);
      }
#pragma unroll 8
      for (int k = 384; k < 512; k += 4) {
        float4 av = *(const float4*)(arow_g + k);
        float4 bv = *(const float4*)(brow + k);
        s2 = fmaf(av.x, bv.x, s2); s2 = fmaf(av.y, bv.y, s2);
        s2 = fmaf(av.z, bv.z, s2); s2 = fmaf(av.w, bv.w, s2);
      }
      myv = (s1 + s2) / SQRT_D;
      key = ((u64)fkey(myv) << 32) | (u64)(u32)(~(u32)myidx);
    }
    key = bitonic64_desc(key, lane);
    myidx = (int)(~(u32)key);
    myv   = (key != 0) ? funkey((u32)(key >> 32)) : -INFINITY;
  }

  // --- weights from sorted lanes 0..31 (m-shift cancels; 1e-8*Z dropped: <=1.5e-5 abs) ---
  const bool selme = (lane < TOPK) && (lane < cnt_eff);
  float mx = __shfl(myv, 0, 64);       // top value
  float e = selme ? __expf(myv - mx) : 0.f;
  float E = e;
#pragma unroll
  for (int off = 32; off > 0; off >>= 1) E += __shfl_xor(E, off, 64);
  float rden = (E > 0.f) ? (1.f / E) : 0.f;
  float w = e * rden;

  // --- dense zero write from registers, drain, then sparse scatter ---
  const float4 z4 = make_float4(0.f, 0.f, 0.f, 0.f);
#pragma unroll
  for (int j = 0; j < 6; ++j) *(float4*)(row + j * 256 + lane * 4) = z4;
  asm volatile("s_waitcnt vmcnt(0)" ::: "memory");   // zeros visible before scatter
  if (selme) row[myidx] = w;

  if (cnt_eff < TOPK && lane >= cnt_eff && lane < TOPK) {   // defensive (never for this input)
    tIdx[(size_t)g * TOPK + lane] = 0; tW[(size_t)g * TOPK + lane] = 0.f;
  }
  if (selme) {
    tIdx[(size_t)g * TOPK + lane] = myidx;
    tW[(size_t)g * TOPK + lane]   = w;
  }
}

// ---------------- out0[b,g] = scale * sum_k w[g,k] * tfT[idx[g,k], b] ----------------
__global__ __launch_bounds__(256) void combine_kernel(const float* __restrict__ tfT, const int* __restrict__ tIdx,
                                                      const float* __restrict__ tW, const float* __restrict__ scalep,
                                                      float* __restrict__ out0)
{
  __shared__ int   sIdx[16 * 32];
  __shared__ float sW[16 * 32];
  const int tid = threadIdx.x;
  const int g0 = blockIdx.x * 16;
  for (int i = tid; i < 512; i += 256) {
    sIdx[i] = tIdx[(size_t)g0 * 32 + i];
    sW[i]   = tW[(size_t)g0 * 32 + i];
  }
  __syncthreads();
  const float scale = scalep[0];
  float acc[16];
#pragma unroll
  for (int gi = 0; gi < 16; ++gi) acc[gi] = 0.f;
#pragma unroll 4
  for (int gi = 0; gi < 16; ++gi) {
    float a = 0.f;
#pragma unroll
    for (int k = 0; k < 32; ++k) {
      float w = sW[gi * 32 + k];
      int t   = sIdx[gi * 32 + k];
      a += w * tfT[(size_t)t * B_DIM + tid];
    }
    acc[gi] = a;
  }
  float* dst = out0 + (size_t)tid * G_ROWS + g0;
#pragma unroll
  for (int q = 0; q < 4; ++q) {
    float4 o = make_float4(scale * acc[4*q], scale * acc[4*q+1], scale * acc[4*q+2], scale * acc[4*q+3]);
    *(float4*)(dst + 4 * q) = o;
  }
}

extern "C" void kernel_launch(void* const* d_in, const int* in_sizes, int n_in,
                              void* d_out, int out_size, void* d_ws, size_t ws_size,
                              hipStream_t stream)
{
  const float* tg_dec     = (const float*)d_in[0];
  const float* tf_base    = (const float*)d_in[1];
  const float* tf_expr    = (const float*)d_in[2];
  const int*   motif_mask = (const int*)d_in[3];
  const float* scale      = (const float*)d_in[4];

  float* out0 = (float*)d_out;                           // [B, G]
  float* attn = out0 + (size_t)B_DIM * G_ROWS;           // [G, T] — Sim scratch, overwritten in place

  char* ws = (char*)d_ws;
  u16*   Ah    = (u16*)(ws);                             // G_PAD*512 bf16
  u16*   Al    = (u16*)(ws + 20578304);
  u16*   Bh    = (u16*)(ws + 41156608);                  // 1536*512 bf16
  u16*   Bl    = (u16*)(ws + 42729472);
  float* tfT   = (float*)(ws + 44302336);                // [T, B] f32
  int*   tIdx  = (int*)(ws + 45875200);                  // [G, 32]
  float* tW    = (float*)(ws + 48435200);                // [G, 32]

  conv_split<<<10048, 256, 0, stream>>>(tg_dec, Ah, Al, G_ROWS);
  conv_split<<<768,   256, 0, stream>>>(tf_base, Bh, Bl, T_DIM);
  transpose_tf<<<dim3(48, 8), dim3(32, 8), 0, stream>>>(tf_expr, tfT);
  gemm_split<<<NWG, 512, 0, stream>>>(Ah, Al, Bh, Bl, attn);
  topk_kernel<<<5000, 256, 0, stream>>>(attn, motif_mask, tg_dec, tf_base, tIdx, tW);
  combine_kernel<<<1250, 256, 0, stream>>>(tfT, tIdx, tW, scale, out0);
}

// Round 2
// 452.495 us; speedup vs baseline: 1.0096x; 1.0096x over previous
//
#include <hip/hip_runtime.h>
#include <cstdint>

typedef unsigned short u16;
typedef unsigned int   u32;
typedef unsigned long long u64;

#define G_ROWS 20000
#define G_PAD  20096      // 157 * 128 (conv padding; gemm over-reads past this, guarded on store)
#define T_DIM  1536
#define D_DIM  512
#define B_DIM  256
#define TOPK   32
#define SIM_SCALE 0.04419417382415922f   // 1/sqrt(512), screening only
#define SQRT_D    22.62741699796952f     // f32(math.sqrt(512)) — np divides by this
#define BOUND_EPS 2.0e-4f                // per-element screen-vs-np error bound (true ~5e-6; 40x margin)

typedef __bf16 bf16x8 __attribute__((ext_vector_type(8)));
typedef float  f32x4  __attribute__((ext_vector_type(4)));

__device__ __forceinline__ u16 f2bf(float f) {
  u32 u = __float_as_uint(f);
  u += 0x7fffu + ((u >> 16) & 1u);   // RNE
  return (u16)(u >> 16);
}
__device__ __forceinline__ float bf2f(u16 h) {
  return __uint_as_float(((u32)h) << 16);
}
__device__ __forceinline__ u32 fkey(float v) {   // order-preserving f32 -> u32
  u32 b = __float_as_uint(v);
  return (b & 0x80000000u) ? ~b : (b | 0x80000000u);
}
__device__ __forceinline__ float funkey(u32 o) {
  u32 b = (o & 0x80000000u) ? (o & 0x7FFFFFFFu) : ~o;
  return __uint_as_float(b);
}

// ---------------- split-conversion: f32 -> (bf16 hi, bf16 lo) ----------------
__global__ __launch_bounds__(256) void conv_split(const float* __restrict__ src,
                                                  u16* __restrict__ hi, u16* __restrict__ lo,
                                                  int valid_rows)
{
  size_t i = ((size_t)blockIdx.x * 256 + threadIdx.x) * 4;
  int row = (int)(i >> 9);
  float4 a = make_float4(0.f, 0.f, 0.f, 0.f);
  if (row < valid_rows) a = *(const float4*)(src + i);
  float v[4] = {a.x, a.y, a.z, a.w};
  u16 h[4], l[4];
#pragma unroll
  for (int c = 0; c < 4; ++c) {
    h[c] = f2bf(v[c]);
    l[c] = f2bf(v[c] - bf2f(h[c]));
  }
  *(uint2*)(hi + i) = make_uint2((u32)h[0] | ((u32)h[1] << 16), (u32)h[2] | ((u32)h[3] << 16));
  *(uint2*)(lo + i) = make_uint2((u32)l[0] | ((u32)l[1] << 16), (u32)l[2] | ((u32)l[3] << 16));
}

// ---------------- tf_expr [B,T] -> tfT [T,B] ----------------
__global__ __launch_bounds__(256) void transpose_tf(const float* __restrict__ in, float* __restrict__ out)
{
  __shared__ float tile[32][33];
  int x = threadIdx.x, y = threadIdx.y;
  int bt = blockIdx.x * 32;
  int bb = blockIdx.y * 32;
#pragma unroll
  for (int i = 0; i < 32; i += 8) tile[y + i][x] = in[(size_t)(bb + y + i) * T_DIM + bt + x];
  __syncthreads();
#pragma unroll
  for (int i = 0; i < 32; i += 8) out[(size_t)(bt + y + i) * B_DIM + bb + x] = tile[x][y + i];
}

// ---------------- async global -> LDS, 16B/lane ----------------
__device__ __forceinline__ void gl16(const u16* g, u16* l) {
  __builtin_amdgcn_global_load_lds((__attribute__((address_space(1))) void*)(void*)g,
                                   (__attribute__((address_space(3))) void*)l, 16, 0, 0);
}

// ---------------- screening GEMM: C ~= (Ah+Al)(Bh+Bl)^T via 3 bf16 MFMA terms ----------------
// 256x128 tile, 8 waves, BK=32, double-buffered LDS (96 KB, 1 block/CU).
// 3-phase-per-K-step schedule (T3+T4): each phase = {ds_reads | half-stage -> raw barrier ->
// lgkmcnt(0)+sched_barrier -> setprio(1) 16 MFMA setprio(0) -> raw barrier}; counted vmcnt(3)
// twice per K-step (never 0 in steady state). Conflict-free subtiled LDS layout (chunk = lane),
// bijective XCD swizzle.
#define NBX 12            // 1536 / 128
#define NWG 948           // 79 * 12  (79 row-panels of 256; last over-reads 128 garbage rows in-workspace)
#define LDS_HALF 24576    // u16 per buffer: Ah 8192 | Al 8192 | Bh 4096 | Bl 4096  (48 KB)

__global__ __launch_bounds__(512, 2) void gemm_split(const u16* __restrict__ Ah, const u16* __restrict__ Al,
                                                     const u16* __restrict__ Bh, const u16* __restrict__ Bl,
                                                     float* __restrict__ Sim)
{
  __shared__ u16 sm[2 * LDS_HALF];   // 96 KB

  // bijective XCD swizzle (m204 variant; NWG % 8 == 4): consecutive wgid on one XCD
  // iterate bx fastest -> the 12 column-blocks of an A row-panel share that XCD's L2.
  const int orig = blockIdx.x;
  const int xcd  = orig & 7;
  const int q    = NWG >> 3, r = NWG & 7;
  const int wgid = (xcd < r ? xcd * (q + 1) : r * (q + 1) + (xcd - r) * q) + (orig >> 3);
  const int by   = wgid / NBX;
  const int bx   = wgid - by * NBX;
  const int bm0  = by * 256;
  const int bn0  = bx * 128;

  const int tid  = threadIdx.x;
  const int lane = tid & 63;
  const int wv   = tid >> 6;      // 0..7
  const int wm   = wv >> 1;       // 0..3 : wave row  (64-row strip)
  const int wn   = wv & 1;        // 0..1 : wave col  (64-col strip)

  // staging lane roles: row = lane&15 within the wave's 16-row subtile, kgroup = lane>>4.
  // LDS dest is linear (base + lane*16B) so chunk index == (kgroup*16 + row) == lane.
  const size_t aOff = (size_t)(bm0 + (wv << 4) + (lane & 15)) * 512 + ((lane >> 4) << 3);
  const size_t bOff = (size_t)(bn0 + (wv << 4) + (lane & 15)) * 512 + ((lane >> 4) << 3);

  f32x4 zero4 = {0.f, 0.f, 0.f, 0.f};
  f32x4 acc[4][4];
#pragma unroll
  for (int i = 0; i < 4; ++i)
#pragma unroll
    for (int j = 0; j < 4; ++j) acc[i][j] = zero4;

  // HI half-tile: Ah (256 rows) + Bh (128 rows); LO half-tile: Al + Bl. 3 gl16 each.
#define STAGE_HI(pb, kt) do {                                      \
    u16* d = sm + (pb) * LDS_HALF + ((wv) << 9);                   \
    const int k0s = (kt) << 5;                                     \
    gl16(Ah + aOff + k0s,         d);                              \
    gl16(Ah + aOff + k0s + 65536, d + 4096);                       \
    gl16(Bh + bOff + k0s,         d + 16384);                      \
  } while (0)
#define STAGE_LO(pb, kt) do {                                      \
    u16* d = sm + (pb) * LDS_HALF + ((wv) << 9);                   \
    const int k0s = (kt) << 5;                                     \
    gl16(Al + aOff + k0s,         d + 8192);                       \
    gl16(Al + aOff + k0s + 65536, d + 12288);                      \
    gl16(Bl + bOff + k0s,         d + 20480);                      \
  } while (0)

  // prologue: stage tile 0 (hi then lo), wait hi landed, sync
  STAGE_HI(0, 0);
  STAGE_LO(0, 0);
  asm volatile("s_waitcnt vmcnt(3)" ::: "memory");   // hi(0) landed; lo(0) in flight
  __builtin_amdgcn_s_barrier();

  const int la8 = lane << 3;

#pragma unroll
  for (int kt = 0; kt < 16; ++kt) {
    const int pb = kt & 1;
    const u16* rb = sm + pb * LDS_HALF;
    bf16x8 aH[4], bH[4], aL[4], bL[4];

    // ---- phase 0: read aH,bH; stage HI(kt+1); wait lo(kt); 16 MFMA aH*bH ----
#pragma unroll
    for (int i = 0; i < 4; ++i) {
      aH[i] = *(const bf16x8*)(rb +         ((((wm << 2) + i) << 9)) + la8);
      bH[i] = *(const bf16x8*)(rb + 16384 + ((((wn << 2) + i) << 9)) + la8);
    }
    if (kt < 15) {
      STAGE_HI(pb ^ 1, kt + 1);
      asm volatile("s_waitcnt vmcnt(3)" ::: "memory");   // out: lo(kt)3 + hi(kt+1)3 -> lo(kt) landed
    } else {
      asm volatile("s_waitcnt vmcnt(0)" ::: "memory");   // epilogue: drain lo(15)
    }
    __builtin_amdgcn_s_barrier();
    asm volatile("s_waitcnt lgkmcnt(0)" ::: "memory");
    __builtin_amdgcn_sched_barrier(0);                   // rule 18: no MFMA hoist above lgkmcnt
    __builtin_amdgcn_s_setprio(1);
#pragma unroll
    for (int mi = 0; mi < 4; ++mi)
#pragma unroll
      for (int ni = 0; ni < 4; ++ni)
        acc[mi][ni] = __builtin_amdgcn_mfma_f32_16x16x32_bf16(aH[mi], bH[ni], acc[mi][ni], 0, 0, 0);
    __builtin_amdgcn_s_setprio(0);
    __builtin_amdgcn_s_barrier();

    // ---- phase 1: read aL; stage LO(kt+1); 16 MFMA aL*bH ----
#pragma unroll
    for (int i = 0; i < 4; ++i)
      aL[i] = *(const bf16x8*)(rb + 8192 + ((((wm << 2) + i) << 9)) + la8);
    if (kt < 15) STAGE_LO(pb ^ 1, kt + 1);
    __builtin_amdgcn_s_barrier();
    asm volatile("s_waitcnt lgkmcnt(0)" ::: "memory");
    __builtin_amdgcn_sched_barrier(0);
    __builtin_amdgcn_s_setprio(1);
#pragma unroll
    for (int mi = 0; mi < 4; ++mi)
#pragma unroll
      for (int ni = 0; ni < 4; ++ni)
        acc[mi][ni] = __builtin_amdgcn_mfma_f32_16x16x32_bf16(aL[mi], bH[ni], acc[mi][ni], 0, 0, 0);
    __builtin_amdgcn_s_setprio(0);
    __builtin_amdgcn_s_barrier();

    // ---- phase 2: read bL; wait hi(kt+1); 16 MFMA aH*bL ----
#pragma unroll
    for (int i = 0; i < 4; ++i)
      bL[i] = *(const bf16x8*)(rb + 20480 + ((((wn << 2) + i) << 9)) + la8);
    if (kt < 15)
      asm volatile("s_waitcnt vmcnt(3)" ::: "memory");   // out: hi(kt+1)3 + lo(kt+1)3 -> hi(kt+1) landed
    __builtin_amdgcn_s_barrier();
    asm volatile("s_waitcnt lgkmcnt(0)" ::: "memory");
    __builtin_amdgcn_sched_barrier(0);
    __builtin_amdgcn_s_setprio(1);
#pragma unroll
    for (int mi = 0; mi < 4; ++mi)
#pragma unroll
      for (int ni = 0; ni < 4; ++ni)
        acc[mi][ni] = __builtin_amdgcn_mfma_f32_16x16x32_bf16(aH[mi], bL[ni], acc[mi][ni], 0, 0, 0);
    __builtin_amdgcn_s_setprio(0);
    __builtin_amdgcn_s_barrier();
  }
#undef STAGE_HI
#undef STAGE_LO

  const int erow0 = bm0 + (wm << 6) + ((lane >> 4) << 2);
  const int ecol0 = bn0 + (wn << 6) + (lane & 15);
#pragma unroll
  for (int mi = 0; mi < 4; ++mi)
#pragma unroll
    for (int rr = 0; rr < 4; ++rr) {
      int row = erow0 + mi * 16 + rr;
      if (row < G_ROWS) {
#pragma unroll
        for (int ni = 0; ni < 4; ++ni)
          Sim[(size_t)row * T_DIM + ecol0 + ni * 16] = acc[mi][ni][rr] * SIM_SCALE;
      }
    }
}

// ---------------- helpers ----------------
__device__ __forceinline__ int count_ge(const float* v, float tau) {
  int c = 0;
#pragma unroll
  for (int j = 0; j < 24; ++j) c += (int)__popcll(__ballot(v[j] >= tau));
  return c;
}
// full 64-lane bitonic sort, descending by u64 key; returns this lane's sorted key
__device__ __forceinline__ u64 bitonic64_desc(u64 key, int lane) {
#pragma unroll
  for (int k = 2; k <= 64; k <<= 1) {
#pragma unroll
    for (int j = k >> 1; j > 0; j >>= 1) {
      u64 p = __shfl_xor(key, j, 64);
      bool lower = (lane & j) == 0;
      bool asc   = (lane & k) != 0;
      u64 mn = (key < p) ? key : p;
      u64 mx = (key < p) ? p : key;
      key = (lower == asc) ? mn : mx;
    }
  }
  return key;
}

// ---------------- per-row (1 wave/row): 6-threshold ladder select, bitonic rank,
// np-replica ONLY when cut is truly contested, register-direct dense write ----------------
__global__ __launch_bounds__(256) void topk_kernel(float* __restrict__ Sim, const int* __restrict__ mask,
                                                   const float* __restrict__ tg_dec,
                                                   const float* __restrict__ tf_base,
                                                   int* __restrict__ tIdx, float* __restrict__ tW)
{
  __shared__ u32 cval[4][64];
  __shared__ int cidxs[4][64];
  const int lane = threadIdx.x & 63;
  const int wv   = threadIdx.x >> 6;
  const int g    = blockIdx.x * 4 + wv;
  float* row = Sim + (size_t)g * T_DIM;
  const int* mrow = mask + (size_t)g * T_DIM;

  // --- vectorized load of sim + mask; apply mask -> -inf ---
  float v[24];
#pragma unroll
  for (int j = 0; j < 6; ++j) {
    float4 q = *(const float4*)(row + j * 256 + lane * 4);
    int4  mq = *(const int4*)(mrow + j * 256 + lane * 4);
    v[j * 4 + 0] = mq.x ? q.x : -INFINITY;
    v[j * 4 + 1] = mq.y ? q.y : -INFINITY;
    v[j * 4 + 2] = mq.z ? q.z : -INFINITY;
    v[j * 4 + 3] = mq.w ? q.w : -INFINITY;
  }

  // --- parallel 6-threshold ladder count (pure VALU) + valid count ---
  const float TH0 = 1.25f, TH1 = 1.40f, TH2 = 1.55f, TH3 = 1.70f, TH4 = 1.85f, TH5 = 2.00f;
  int n0 = 0, n1 = 0, n2 = 0, n3 = 0, n4 = 0, n5 = 0, nv = 0;
#pragma unroll
  for (int j = 0; j < 24; ++j) {
    float x = v[j];
    n0 += (x >= TH0); n1 += (x >= TH1); n2 += (x >= TH2);
    n3 += (x >= TH3); n4 += (x >= TH4); n5 += (x >= TH5);
    nv += (x != -INFINITY);
  }
  // pack 16-bit fields into two u64s, one shfl-reduce pass
  u64 p0 = (u64)(u32)n0 | ((u64)(u32)n1 << 16) | ((u64)(u32)n2 << 32) | ((u64)(u32)n3 << 48);
  u64 p1 = (u64)(u32)n4 | ((u64)(u32)n5 << 16) | ((u64)(u32)nv << 32);
#pragma unroll
  for (int off = 32; off > 0; off >>= 1) {
    p0 += __shfl_xor(p0, off, 64);
    p1 += __shfl_xor(p1, off, 64);
  }
  int c[6];
  c[0] = (int)(p0 & 0xFFFF); c[1] = (int)((p0 >> 16) & 0xFFFF);
  c[2] = (int)((p0 >> 32) & 0xFFFF); c[3] = (int)((p0 >> 48) & 0xFFFF);
  c[4] = (int)(p1 & 0xFFFF); c[5] = (int)((p1 >> 16) & 0xFFFF);
  const int cvalid = (int)((p1 >> 32) & 0xFFFF);

  // --- pick largest threshold with count >= 33; fallback bisect for gaps/extremes (~1%) ---
  float tau; int cnt;
  if (cvalid <= 64) { tau = -3.0e38f; cnt = cvalid; }
  else {
    int is = -1;
#pragma unroll
    for (int i = 0; i < 6; ++i) if (c[i] >= 33) is = i;
    const float THv[7] = {TH0, TH1, TH2, TH3, TH4, TH5, 8.0f};
    if (is >= 0 && c[is] <= 64) { tau = THv[is]; cnt = c[is]; }
    else {
      float lo, hi;
      if (is < 0) { lo = -4.0f; hi = TH0; }         // even TH0 keeps <33 (tiny-scale row)
      else        { lo = THv[is]; hi = THv[is + 1]; } // gap: count(lo)>64, count(hi)<33
      tau = lo; cnt = 1000;
      for (int it = 0; it < 16; ++it) {
        float mid = 0.5f * (lo + hi);
        int cm = count_ge(v, mid);
        if (cm > 64)      lo = mid;
        else if (cm < 33) hi = mid;
        else { tau = mid; cnt = cm; break; }
      }
      if (cnt == 1000) tau = lo;                    // exact-tie pathology; compaction clamps
    }
  }

  // --- ballot-prefix compaction into wave-private LDS ---
  int base = 0;
#pragma unroll
  for (int j = 0; j < 24; ++j) {
    bool pred = (v[j] >= tau);
    u64 bmc = __ballot(pred);
    int pos = base + (int)__popcll(bmc & ((1ull << lane) - 1ull));
    int idx = (j >> 2) * 256 + lane * 4 + (j & 3);
    if (pred && pos < 64) { cval[wv][pos] = fkey(v[j]); cidxs[wv][pos] = idx; }
    base += (int)__popcll(bmc);
  }
  const int cnt_eff = (base < 64) ? base : 64;

  u64 key = 0;
  if (lane < cnt_eff)
    key = ((u64)cval[wv][lane] << 32) | (u64)(u32)(~(u32)cidxs[wv][lane]);

  // --- bitonic sort: lane L = L-th largest (value desc, idx asc) ---
  key = bitonic64_desc(key, lane);
  int   myidx = (int)(~(u32)key);
  float myv   = (key != 0) ? funkey((u32)(key >> 32)) : -INFINITY;

  // --- np-replica ONLY if the 31/32 cut is truly contested: v31 - v32 < 2*eps ---
  float v31 = __shfl(myv, 31, 64);
  float v32 = __shfl(myv, 32, 64);
  if (cnt_eff > TOPK && (v31 - v32) < 2.0f * BOUND_EPS) {
    bool flag = (lane < cnt_eff) &&
                (myv >= v32 - 2.0f * BOUND_EPS) && (myv <= v31 + 2.0f * BOUND_EPS);
    if (flag) {
      // bit-exact np replica: OpenBLAS sgemm sequential-K FMA chain, kc split 384|128,
      // then f32 division by f32(sqrt(512)). Requires strict FP (no fast-math).
      const float* arow_g = tg_dec + (size_t)g * D_DIM;
      const float* brow   = tf_base + (size_t)myidx * D_DIM;
      float s1 = 0.f, s2 = 0.f;
#pragma unroll 8
      for (int k = 0; k < 384; k += 4) {
        float4 av = *(const float4*)(arow_g + k);
        float4 bv = *(const float4*)(brow + k);
        s1 = fmaf(av.x, bv.x, s1); s1 = fmaf(av.y, bv.y, s1);
        s1 = fmaf(av.z, bv.z, s1); s1 = fmaf(av.w, bv.w, s1);
      }
#pragma unroll 8
      for (int k = 384; k < 512; k += 4) {
        float4 av = *(const float4*)(arow_g + k);
        float4 bv = *(const float4*)(brow + k);
        s2 = fmaf(av.x, bv.x, s2); s2 = fmaf(av.y, bv.y, s2);
        s2 = fmaf(av.z, bv.z, s2); s2 = fmaf(av.w, bv.w, s2);
      }
      myv = (s1 + s2) / SQRT_D;
      key = ((u64)fkey(myv) << 32) | (u64)(u32)(~(u32)myidx);
    }
    key = bitonic64_desc(key, lane);
    myidx = (int)(~(u32)key);
    myv   = (key != 0) ? funkey((u32)(key >> 32)) : -INFINITY;
  }

  // --- weights from sorted lanes 0..31 (m-shift cancels; 1e-8*Z dropped: <=1.5e-5 abs) ---
  const bool selme = (lane < TOPK) && (lane < cnt_eff);
  float mx = __shfl(myv, 0, 64);       // top value
  float e = selme ? __expf(myv - mx) : 0.f;
  float E = e;
#pragma unroll
  for (int off = 32; off > 0; off >>= 1) E += __shfl_xor(E, off, 64);
  float rden = (E > 0.f) ? (1.f / E) : 0.f;
  float w = e * rden;

  // --- dense zero write from registers, drain, then sparse scatter ---
  const float4 z4 = make_float4(0.f, 0.f, 0.f, 0.f);
#pragma unroll
  for (int j = 0; j < 6; ++j) *(float4*)(row + j * 256 + lane * 4) = z4;
  asm volatile("s_waitcnt vmcnt(0)" ::: "memory");   // zeros visible before scatter
  if (selme) row[myidx] = w;

  if (cnt_eff < TOPK && lane >= cnt_eff && lane < TOPK) {   // defensive (never for this input)
    tIdx[(size_t)g * TOPK + lane] = 0; tW[(size_t)g * TOPK + lane] = 0.f;
  }
  if (selme) {
    tIdx[(size_t)g * TOPK + lane] = myidx;
    tW[(size_t)g * TOPK + lane]   = w;
  }
}

// ---------------- out0[b,g] = scale * sum_k w[g,k] * tfT[idx[g,k], b] ----------------
__global__ __launch_bounds__(256) void combine_kernel(const float* __restrict__ tfT, const int* __restrict__ tIdx,
                                                      const float* __restrict__ tW, const float* __restrict__ scalep,
                                                      float* __restrict__ out0)
{
  __shared__ int   sIdx[16 * 32];
  __shared__ float sW[16 * 32];
  const int tid = threadIdx.x;
  const int g0 = blockIdx.x * 16;
  for (int i = tid; i < 512; i += 256) {
    sIdx[i] = tIdx[(size_t)g0 * 32 + i];
    sW[i]   = tW[(size_t)g0 * 32 + i];
  }
  __syncthreads();
  const float scale = scalep[0];
  float acc[16];
#pragma unroll
  for (int gi = 0; gi < 16; ++gi) acc[gi] = 0.f;
#pragma unroll 4
  for (int gi = 0; gi < 16; ++gi) {
    float a = 0.f;
#pragma unroll
    for (int k = 0; k < 32; ++k) {
      float w = sW[gi * 32 + k];
      int t   = sIdx[gi * 32 + k];
      a += w * tfT[(size_t)t * B_DIM + tid];
    }
    acc[gi] = a;
  }
  float* dst = out0 + (size_t)tid * G_ROWS + g0;
#pragma unroll
  for (int q = 0; q < 4; ++q) {
    float4 o = make_float4(scale * acc[4*q], scale * acc[4*q+1], scale * acc[4*q+2], scale * acc[4*q+3]);
    *(float4*)(dst + 4 * q) = o;
  }
}

extern "C" void kernel_launch(void* const* d_in, const int* in_sizes, int n_in,
                              void* d_out, int out_size, void* d_ws, size_t ws_size,
                              hipStream_t stream)
{
  const float* tg_dec     = (const float*)d_in[0];
  const float* tf_base    = (const float*)d_in[1];
  const float* tf_expr    = (const float*)d_in[2];
  const int*   motif_mask = (const int*)d_in[3];
  const float* scale      = (const float*)d_in[4];

  float* out0 = (float*)d_out;                           // [B, G]
  float* attn = out0 + (size_t)B_DIM * G_ROWS;           // [G, T] — Sim scratch, overwritten in place

  char* ws = (char*)d_ws;
  u16*   Ah    = (u16*)(ws);                             // G_PAD*512 bf16
  u16*   Al    = (u16*)(ws + 20578304);
  u16*   Bh    = (u16*)(ws + 41156608);                  // 1536*512 bf16
  u16*   Bl    = (u16*)(ws + 42729472);
  float* tfT   = (float*)(ws + 44302336);                // [T, B] f32
  int*   tIdx  = (int*)(ws + 45875200);                  // [G, 32]
  float* tW    = (float*)(ws + 48435200);                // [G, 32]

  conv_split<<<10048, 256, 0, stream>>>(tg_dec, Ah, Al, G_ROWS);
  conv_split<<<768,   256, 0, stream>>>(tf_base, Bh, Bl, T_DIM);
  transpose_tf<<<dim3(48, 8), dim3(32, 8), 0, stream>>>(tf_expr, tfT);
  gemm_split<<<NWG, 512, 0, stream>>>(Ah, Al, Bh, Bl, attn);
  topk_kernel<<<5000, 256, 0, stream>>>(attn, motif_mask, tg_dec, tf_base, tIdx, tW);
  combine_kernel<<<1250, 256, 0, stream>>>(tfT, tIdx, tW, scale, out0);
}

// Round 3
// 424.975 us; speedup vs baseline: 1.0750x; 1.0648x over previous
//
#include <hip/hip_runtime.h>
#include <cstdint>

typedef unsigned short u16;
typedef unsigned int   u32;
typedef unsigned long long u64;

#define G_ROWS 20000
#define G_PAD  20096      // 157 * 128 (conv padding; gemm over-reads past this, guarded on store)
#define T_DIM  1536
#define D_DIM  512
#define B_DIM  256
#define TOPK   32
#define SIM_SCALE 0.04419417382415922f   // 1/sqrt(512), screening only
#define SQRT_D    22.62741699796952f     // f32(math.sqrt(512)) — np divides by this
#define BOUND_EPS 2.0e-4f                // per-element screen-vs-np error bound (true ~5e-6; 40x margin)

typedef __bf16 bf16x8 __attribute__((ext_vector_type(8)));
typedef float  f32x4  __attribute__((ext_vector_type(4)));

__device__ __forceinline__ u16 f2bf(float f) {
  u32 u = __float_as_uint(f);
  u += 0x7fffu + ((u >> 16) & 1u);   // RNE
  return (u16)(u >> 16);
}
__device__ __forceinline__ float bf2f(u16 h) {
  return __uint_as_float(((u32)h) << 16);
}
__device__ __forceinline__ u32 fkey(float v) {   // order-preserving f32 -> u32
  u32 b = __float_as_uint(v);
  return (b & 0x80000000u) ? ~b : (b | 0x80000000u);
}
__device__ __forceinline__ float funkey(u32 o) {
  u32 b = (o & 0x80000000u) ? (o & 0x7FFFFFFFu) : ~o;
  return __uint_as_float(b);
}

// ---------------- fused preprocessing: convA | convB | transpose ----------------
// blocks [0, 10048): conv tg_dec -> Ah/Al ; [10048, 10816): conv tf_base -> Bh/Bl ;
// [10816, 11200): transpose tf_expr [B,T] -> tfT [T,B]
__global__ __launch_bounds__(256) void prep(const float* __restrict__ tg_dec,
                                            const float* __restrict__ tf_base,
                                            const float* __restrict__ tf_expr,
                                            u16* __restrict__ Ah, u16* __restrict__ Al,
                                            u16* __restrict__ Bh, u16* __restrict__ Bl,
                                            float* __restrict__ tfT)
{
  __shared__ float tile[32][33];
  const int b = blockIdx.x;
  const int tid = threadIdx.x;
  if (b < 10816) {
    const float* src; u16 *hi, *lo; int valid_rows; int bb;
    if (b < 10048) { src = tg_dec; hi = Ah; lo = Al; valid_rows = G_ROWS; bb = b; }
    else           { src = tf_base; hi = Bh; lo = Bl; valid_rows = T_DIM; bb = b - 10048; }
    size_t i = ((size_t)bb * 256 + tid) * 4;
    int row = (int)(i >> 9);
    float4 a = make_float4(0.f, 0.f, 0.f, 0.f);
    if (row < valid_rows) a = *(const float4*)(src + i);
    float v[4] = {a.x, a.y, a.z, a.w};
    u16 h[4], l[4];
#pragma unroll
    for (int c = 0; c < 4; ++c) {
      h[c] = f2bf(v[c]);
      l[c] = f2bf(v[c] - bf2f(h[c]));
    }
    *(uint2*)(hi + i) = make_uint2((u32)h[0] | ((u32)h[1] << 16), (u32)h[2] | ((u32)h[3] << 16));
    *(uint2*)(lo + i) = make_uint2((u32)l[0] | ((u32)l[1] << 16), (u32)l[2] | ((u32)l[3] << 16));
  } else {
    const int t = b - 10816;
    const int x = tid & 31, y = tid >> 5;
    const int bt = (t % 48) * 32;
    const int bb = (t / 48) * 32;
#pragma unroll
    for (int i = 0; i < 32; i += 8) tile[y + i][x] = tf_expr[(size_t)(bb + y + i) * T_DIM + bt + x];
    __syncthreads();
#pragma unroll
    for (int i = 0; i < 32; i += 8) tfT[(size_t)(bt + y + i) * B_DIM + bb + x] = tile[x][y + i];
  }
}

// ---------------- async global -> LDS, 16B/lane ----------------
__device__ __forceinline__ void gl16(const u16* g, u16* l) {
  __builtin_amdgcn_global_load_lds((__attribute__((address_space(1))) void*)(void*)g,
                                   (__attribute__((address_space(3))) void*)l, 16, 0, 0);
}

// ---------------- screening GEMM: C ~= (Ah+Al)(Bh+Bl)^T via 3 bf16 MFMA terms ----------------
// m201-cadence port: 256x256 tile, BK=32, 8 waves (wm,wn)=(2,4) wave tile 128x64,
// 4 half-buffers (A0/A1/B0/B1, 32 KB each = 128 KiB LDS).
// Stage issue decoupled from consume: B(kt+1)@Ph1(kt), A(kt+2)@Ph3(kt); consume-wait vmcnt(4)
// (never 0 in loop). 4 phases/tile, each {ds_read | stage -> barrier -> lgkm -> 24 MFMA -> barrier}.
// Conflict-free lane-order subtile LDS layout; bijective XCD swizzle.
#define NBX 6             // 1536 / 256
#define NWG 474           // 79 * 6  (79 row-panels of 256; last over-reads garbage rows in-workspace)

__global__ __launch_bounds__(512, 2) void gemm_split(const u16* __restrict__ Ah, const u16* __restrict__ Al,
                                                     const u16* __restrict__ Bh, const u16* __restrict__ Bl,
                                                     float* __restrict__ Sim)
{
  // u16 map: A-buf p at p*16384 (Ah 8192 | Al 8192); B-buf p at 32768 + p*16384 (Bh | Bl)
  __shared__ u16 sm[65536];   // 128 KiB

  // bijective XCD swizzle (m204; NWG % 8 == 2)
  const int orig = blockIdx.x;
  const int xcd  = orig & 7;
  const int q    = NWG >> 3, r = NWG & 7;
  const int wgid = (xcd < r ? xcd * (q + 1) : r * (q + 1) + (xcd - r) * q) + (orig >> 3);
  const int by   = wgid / NBX;
  const int bx   = wgid - by * NBX;
  const int bm0  = by * 256;
  const int bn0  = bx * 256;

  const int tid  = threadIdx.x;
  const int lane = tid & 63;
  const int wv   = tid >> 6;      // 0..7
  const int wm   = wv >> 2;       // 0..1 : wave row  (128-row strip)
  const int wn   = wv & 3;        // 0..3 : wave col  (64-col strip)
  const int la8  = lane << 3;     // u16 offset of this lane's 16B chunk in a subtile

  // staging roles: wave wv stages subtiles {2wv, 2wv+1} of each region.
  // subtile s = 16 rows x 32 k, stored as 64 chunks of 16B in lane order (chunk l = lane l).
  const int sub  = wv << 1;
  const int srow = lane & 15;
  const int skc  = (lane >> 4) << 3;
  const u16* gA0 = Ah + (size_t)(bm0 + (sub + 0) * 16 + srow) * 512 + skc;
  const u16* gA1 = Ah + (size_t)(bm0 + (sub + 1) * 16 + srow) * 512 + skc;
  const u16* gAl0 = Al + (size_t)(bm0 + (sub + 0) * 16 + srow) * 512 + skc;
  const u16* gAl1 = Al + (size_t)(bm0 + (sub + 1) * 16 + srow) * 512 + skc;
  const u16* gB0 = Bh + (size_t)(bn0 + (sub + 0) * 16 + srow) * 512 + skc;
  const u16* gB1 = Bh + (size_t)(bn0 + (sub + 1) * 16 + srow) * 512 + skc;
  const u16* gBl0 = Bl + (size_t)(bn0 + (sub + 0) * 16 + srow) * 512 + skc;
  const u16* gBl1 = Bl + (size_t)(bn0 + (sub + 1) * 16 + srow) * 512 + skc;

#define STAGE_A(p, ktn) do {                                   \
    const size_t ko = (size_t)(ktn) << 5;                      \
    u16* d = sm + (p) * 16384 + sub * 512;                     \
    gl16(gA0 + ko,  d);                                        \
    gl16(gA1 + ko,  d + 512);                                  \
    gl16(gAl0 + ko, d + 8192);                                 \
    gl16(gAl1 + ko, d + 8192 + 512);                           \
  } while (0)
#define STAGE_B(p, ktn) do {                                   \
    const size_t ko = (size_t)(ktn) << 5;                      \
    u16* d = sm + 32768 + (p) * 16384 + sub * 512;             \
    gl16(gB0 + ko,  d);                                        \
    gl16(gB1 + ko,  d + 512);                                  \
    gl16(gBl0 + ko, d + 8192);                                 \
    gl16(gBl1 + ko, d + 8192 + 512);                           \
  } while (0)

  f32x4 acc[8][4];
#pragma unroll
  for (int i = 0; i < 8; ++i)
#pragma unroll
    for (int j = 0; j < 4; ++j) acc[i][j] = (f32x4){0.f, 0.f, 0.f, 0.f};

  bf16x8 aH[4], aL[4], bH[4], bL[4];

#define READ_A(rbA, half) do {                                                     \
    _Pragma("unroll")                                                              \
    for (int i = 0; i < 4; ++i) {                                                  \
      aH[i] = *(const bf16x8*)((rbA) + (wm * 8 + (half) * 4 + i) * 512 + la8);     \
      aL[i] = *(const bf16x8*)((rbA) + 8192 + (wm * 8 + (half) * 4 + i) * 512 + la8); \
    }                                                                              \
  } while (0)
#define READ_B(rbB, half) do {                                                     \
    _Pragma("unroll")                                                              \
    for (int i = 0; i < 2; ++i) {                                                  \
      bH[(half) * 2 + i] = *(const bf16x8*)((rbB) + (wn * 4 + (half) * 2 + i) * 512 + la8); \
      bL[(half) * 2 + i] = *(const bf16x8*)((rbB) + 8192 + (wn * 4 + (half) * 2 + i) * 512 + la8); \
    }                                                                              \
  } while (0)
#define MFMA_Q(qm, qn) do {                                                        \
    __builtin_amdgcn_s_setprio(1);                                                 \
    _Pragma("unroll")                                                              \
    for (int m2 = 0; m2 < 4; ++m2)                                                 \
      _Pragma("unroll")                                                            \
      for (int n2 = 0; n2 < 2; ++n2) {                                             \
        const int mi = (qm) * 4 + m2, ni = (qn) * 2 + n2;                          \
        acc[mi][ni] = __builtin_amdgcn_mfma_f32_16x16x32_bf16(aH[m2], bH[ni], acc[mi][ni], 0, 0, 0); \
        acc[mi][ni] = __builtin_amdgcn_mfma_f32_16x16x32_bf16(aH[m2], bL[ni], acc[mi][ni], 0, 0, 0); \
        acc[mi][ni] = __builtin_amdgcn_mfma_f32_16x16x32_bf16(aL[m2], bH[ni], acc[mi][ni], 0, 0, 0); \
      }                                                                            \
    __builtin_amdgcn_s_setprio(0);                                                 \
  } while (0)
#define LGKM0 do { asm volatile("s_waitcnt lgkmcnt(0)" ::: "memory"); __builtin_amdgcn_sched_barrier(0); } while (0)
#define BAR   do { __builtin_amdgcn_sched_barrier(0); __builtin_amdgcn_s_barrier(); } while (0)

  // prologue: A(0), B(0), A(1) in flight (12 loads)
  STAGE_A(0, 0);
  STAGE_B(0, 0);
  STAGE_A(1, 1);

#pragma unroll 2
  for (int kt = 0; kt < 16; ++kt) {
    const u16* rbA = sm + (kt & 1) * 16384;
    const u16* rbB = sm + 32768 + (kt & 1) * 16384;

    // ---- Ph0: handshake for tile kt (A(kt),B(kt) landed; A(kt+1) stays in flight) ----
    asm volatile("s_waitcnt vmcnt(4)" ::: "memory");
    BAR;
    READ_A(rbA, 0);                 // aH/aL frags 0-3 (rows wm*128 .. +63)
    READ_B(rbB, 0);                 // bH/bL frags 0-1
    LGKM0;
    MFMA_Q(0, 0);
    BAR;

    // ---- Ph1: stage B(kt+1) (its buffer free since tile kt-1); read b-half 1 ----
    if (kt < 15) STAGE_B((kt + 1) & 1, kt + 1);
    READ_B(rbB, 1);                 // bH/bL frags 2-3
    LGKM0;
    MFMA_Q(0, 1);
    BAR;

    // ---- Ph2: read a-half 1 (overwrites aH/aL regs; Q00/Q01 already consumed them) ----
    READ_A(rbA, 1);                 // aH/aL frags 4-7
    LGKM0;
    MFMA_Q(1, 0);
    BAR;                            // all waves done reading A-buf[kt&1]

    // ---- Ph3: stage A(kt+2) into A-buf[kt&1] (safe: reads retired at Ph2 barrier) ----
    if (kt < 14) STAGE_A(kt & 1, kt + 2);
    MFMA_Q(1, 1);
    // no barrier: Ph0(kt+1)'s vmcnt+barrier is the next sync point
  }
#undef STAGE_A
#undef STAGE_B
#undef READ_A
#undef READ_B
#undef MFMA_Q
#undef LGKM0
#undef BAR

  const int erow0 = bm0 + (wm << 7) + ((lane >> 4) << 2);
  const int ecol0 = bn0 + (wn << 6) + (lane & 15);
#pragma unroll
  for (int mi = 0; mi < 8; ++mi)
#pragma unroll
    for (int rr = 0; rr < 4; ++rr) {
      int row = erow0 + mi * 16 + rr;
      if (row < G_ROWS) {
#pragma unroll
        for (int ni = 0; ni < 4; ++ni)
          Sim[(size_t)row * T_DIM + ecol0 + ni * 16] = acc[mi][ni][rr] * SIM_SCALE;
      }
    }
}

// ---------------- helpers ----------------
__device__ __forceinline__ int count_ge(const float* v, float tau) {
  int c = 0;
#pragma unroll
  for (int j = 0; j < 24; ++j) c += (int)__popcll(__ballot(v[j] >= tau));
  return c;
}
// full 64-lane bitonic sort, descending by u64 key; returns this lane's sorted key
__device__ __forceinline__ u64 bitonic64_desc(u64 key, int lane) {
#pragma unroll
  for (int k = 2; k <= 64; k <<= 1) {
#pragma unroll
    for (int j = k >> 1; j > 0; j >>= 1) {
      u64 p = __shfl_xor(key, j, 64);
      bool lower = (lane & j) == 0;
      bool asc   = (lane & k) != 0;
      u64 mn = (key < p) ? key : p;
      u64 mx = (key < p) ? p : key;
      key = (lower == asc) ? mn : mx;
    }
  }
  return key;
}

// ---------------- per-row (1 wave/row): 6-threshold ladder select, bitonic rank,
// np-replica ONLY when cut is truly contested, register-direct dense write ----------------
__global__ __launch_bounds__(256) void topk_kernel(float* __restrict__ Sim, const int* __restrict__ mask,
                                                   const float* __restrict__ tg_dec,
                                                   const float* __restrict__ tf_base,
                                                   int* __restrict__ tIdx, float* __restrict__ tW)
{
  __shared__ u32 cval[4][64];
  __shared__ int cidxs[4][64];
  const int lane = threadIdx.x & 63;
  const int wv   = threadIdx.x >> 6;
  const int g    = blockIdx.x * 4 + wv;
  float* row = Sim + (size_t)g * T_DIM;
  const int* mrow = mask + (size_t)g * T_DIM;

  // --- vectorized load of sim + mask; apply mask -> -inf ---
  float v[24];
#pragma unroll
  for (int j = 0; j < 6; ++j) {
    float4 q = *(const float4*)(row + j * 256 + lane * 4);
    int4  mq = *(const int4*)(mrow + j * 256 + lane * 4);
    v[j * 4 + 0] = mq.x ? q.x : -INFINITY;
    v[j * 4 + 1] = mq.y ? q.y : -INFINITY;
    v[j * 4 + 2] = mq.z ? q.z : -INFINITY;
    v[j * 4 + 3] = mq.w ? q.w : -INFINITY;
  }

  // --- parallel 6-threshold ladder count (pure VALU) + valid count ---
  const float TH0 = 1.25f, TH1 = 1.40f, TH2 = 1.55f, TH3 = 1.70f, TH4 = 1.85f, TH5 = 2.00f;
  int n0 = 0, n1 = 0, n2 = 0, n3 = 0, n4 = 0, n5 = 0, nv = 0;
#pragma unroll
  for (int j = 0; j < 24; ++j) {
    float x = v[j];
    n0 += (x >= TH0); n1 += (x >= TH1); n2 += (x >= TH2);
    n3 += (x >= TH3); n4 += (x >= TH4); n5 += (x >= TH5);
    nv += (x != -INFINITY);
  }
  // pack 16-bit fields into two u64s, one shfl-reduce pass
  u64 p0 = (u64)(u32)n0 | ((u64)(u32)n1 << 16) | ((u64)(u32)n2 << 32) | ((u64)(u32)n3 << 48);
  u64 p1 = (u64)(u32)n4 | ((u64)(u32)n5 << 16) | ((u64)(u32)nv << 32);
#pragma unroll
  for (int off = 32; off > 0; off >>= 1) {
    p0 += __shfl_xor(p0, off, 64);
    p1 += __shfl_xor(p1, off, 64);
  }
  int c[6];
  c[0] = (int)(p0 & 0xFFFF); c[1] = (int)((p0 >> 16) & 0xFFFF);
  c[2] = (int)((p0 >> 32) & 0xFFFF); c[3] = (int)((p0 >> 48) & 0xFFFF);
  c[4] = (int)(p1 & 0xFFFF); c[5] = (int)((p1 >> 16) & 0xFFFF);
  const int cvalid = (int)((p1 >> 32) & 0xFFFF);

  // --- pick largest threshold with count >= 33; fallback bisect for gaps/extremes (~1%) ---
  float tau; int cnt;
  if (cvalid <= 64) { tau = -3.0e38f; cnt = cvalid; }
  else {
    int is = -1;
#pragma unroll
    for (int i = 0; i < 6; ++i) if (c[i] >= 33) is = i;
    const float THv[7] = {TH0, TH1, TH2, TH3, TH4, TH5, 8.0f};
    if (is >= 0 && c[is] <= 64) { tau = THv[is]; cnt = c[is]; }
    else {
      float lo, hi;
      if (is < 0) { lo = -4.0f; hi = TH0; }         // even TH0 keeps <33 (tiny-scale row)
      else        { lo = THv[is]; hi = THv[is + 1]; } // gap: count(lo)>64, count(hi)<33
      tau = lo; cnt = 1000;
      for (int it = 0; it < 16; ++it) {
        float mid = 0.5f * (lo + hi);
        int cm = count_ge(v, mid);
        if (cm > 64)      lo = mid;
        else if (cm < 33) hi = mid;
        else { tau = mid; cnt = cm; break; }
      }
      if (cnt == 1000) tau = lo;                    // exact-tie pathology; compaction clamps
    }
  }

  // --- ballot-prefix compaction into wave-private LDS ---
  int base = 0;
#pragma unroll
  for (int j = 0; j < 24; ++j) {
    bool pred = (v[j] >= tau);
    u64 bmc = __ballot(pred);
    int pos = base + (int)__popcll(bmc & ((1ull << lane) - 1ull));
    int idx = (j >> 2) * 256 + lane * 4 + (j & 3);
    if (pred && pos < 64) { cval[wv][pos] = fkey(v[j]); cidxs[wv][pos] = idx; }
    base += (int)__popcll(bmc);
  }
  const int cnt_eff = (base < 64) ? base : 64;

  u64 key = 0;
  if (lane < cnt_eff)
    key = ((u64)cval[wv][lane] << 32) | (u64)(u32)(~(u32)cidxs[wv][lane]);

  // --- bitonic sort: lane L = L-th largest (value desc, idx asc) ---
  key = bitonic64_desc(key, lane);
  int   myidx = (int)(~(u32)key);
  float myv   = (key != 0) ? funkey((u32)(key >> 32)) : -INFINITY;

  // --- np-replica ONLY if the 31/32 cut is truly contested: v31 - v32 < 2*eps ---
  float v31 = __shfl(myv, 31, 64);
  float v32 = __shfl(myv, 32, 64);
  if (cnt_eff > TOPK && (v31 - v32) < 2.0f * BOUND_EPS) {
    bool flag = (lane < cnt_eff) &&
                (myv >= v32 - 2.0f * BOUND_EPS) && (myv <= v31 + 2.0f * BOUND_EPS);
    if (flag) {
      // bit-exact np replica: OpenBLAS sgemm sequential-K FMA chain, kc split 384|128,
      // then f32 division by f32(sqrt(512)). Requires strict FP (no fast-math).
      const float* arow_g = tg_dec + (size_t)g * D_DIM;
      const float* brow   = tf_base + (size_t)myidx * D_DIM;
      float s1 = 0.f, s2 = 0.f;
#pragma unroll 8
      for (int k = 0; k < 384; k += 4) {
        float4 av = *(const float4*)(arow_g + k);
        float4 bv = *(const float4*)(brow + k);
        s1 = fmaf(av.x, bv.x, s1); s1 = fmaf(av.y, bv.y, s1);
        s1 = fmaf(av.z, bv.z, s1); s1 = fmaf(av.w, bv.w, s1);
      }
#pragma unroll 8
      for (int k = 384; k < 512; k += 4) {
        float4 av = *(const float4*)(arow_g + k);
        float4 bv = *(const float4*)(brow + k);
        s2 = fmaf(av.x, bv.x, s2); s2 = fmaf(av.y, bv.y, s2);
        s2 = fmaf(av.z, bv.z, s2); s2 = fmaf(av.w, bv.w, s2);
      }
      myv = (s1 + s2) / SQRT_D;
      key = ((u64)fkey(myv) << 32) | (u64)(u32)(~(u32)myidx);
    }
    key = bitonic64_desc(key, lane);
    myidx = (int)(~(u32)key);
    myv   = (key != 0) ? funkey((u32)(key >> 32)) : -INFINITY;
  }

  // --- weights from sorted lanes 0..31 (m-shift cancels; 1e-8*Z dropped: <=1.5e-5 abs) ---
  const bool selme = (lane < TOPK) && (lane < cnt_eff);
  float mx = __shfl(myv, 0, 64);       // top value
  float e = selme ? __expf(myv - mx) : 0.f;
  float E = e;
#pragma unroll
  for (int off = 32; off > 0; off >>= 1) E += __shfl_xor(E, off, 64);
  float rden = (E > 0.f) ? (1.f / E) : 0.f;
  float w = e * rden;

  // --- dense zero write from registers, drain, then sparse scatter ---
  const float4 z4 = make_float4(0.f, 0.f, 0.f, 0.f);
#pragma unroll
  for (int j = 0; j < 6; ++j) *(float4*)(row + j * 256 + lane * 4) = z4;
  asm volatile("s_waitcnt vmcnt(0)" ::: "memory");   // zeros visible before scatter
  if (selme) row[myidx] = w;

  if (cnt_eff < TOPK && lane >= cnt_eff && lane < TOPK) {   // defensive (never for this input)
    tIdx[(size_t)g * TOPK + lane] = 0; tW[(size_t)g * TOPK + lane] = 0.f;
  }
  if (selme) {
    tIdx[(size_t)g * TOPK + lane] = myidx;
    tW[(size_t)g * TOPK + lane]   = w;
  }
}

// ---------------- out0[b,g] = scale * sum_k w[g,k] * tfT[idx[g,k], b] ----------------
__global__ __launch_bounds__(256) void combine_kernel(const float* __restrict__ tfT, const int* __restrict__ tIdx,
                                                      const float* __restrict__ tW, const float* __restrict__ scalep,
                                                      float* __restrict__ out0)
{
  __shared__ int   sIdx[16 * 32];
  __shared__ float sW[16 * 32];
  const int tid = threadIdx.x;
  const int g0 = blockIdx.x * 16;
  for (int i = tid; i < 512; i += 256) {
    sIdx[i] = tIdx[(size_t)g0 * 32 + i];
    sW[i]   = tW[(size_t)g0 * 32 + i];
  }
  __syncthreads();
  const float scale = scalep[0];
  float acc[16];
#pragma unroll
  for (int gi = 0; gi < 16; ++gi) acc[gi] = 0.f;
#pragma unroll 4
  for (int gi = 0; gi < 16; ++gi) {
    float a = 0.f;
#pragma unroll
    for (int k = 0; k < 32; ++k) {
      float w = sW[gi * 32 + k];
      int t   = sIdx[gi * 32 + k];
      a += w * tfT[(size_t)t * B_DIM + tid];
    }
    acc[gi] = a;
  }
  float* dst = out0 + (size_t)tid * G_ROWS + g0;
#pragma unroll
  for (int q = 0; q < 4; ++q) {
    float4 o = make_float4(scale * acc[4*q], scale * acc[4*q+1], scale * acc[4*q+2], scale * acc[4*q+3]);
    *(float4*)(dst + 4 * q) = o;
  }
}

extern "C" void kernel_launch(void* const* d_in, const int* in_sizes, int n_in,
                              void* d_out, int out_size, void* d_ws, size_t ws_size,
                              hipStream_t stream)
{
  const float* tg_dec     = (const float*)d_in[0];
  const float* tf_base    = (const float*)d_in[1];
  const float* tf_expr    = (const float*)d_in[2];
  const int*   motif_mask = (const int*)d_in[3];
  const float* scale      = (const float*)d_in[4];

  float* out0 = (float*)d_out;                           // [B, G]
  float* attn = out0 + (size_t)B_DIM * G_ROWS;           // [G, T] — Sim scratch, overwritten in place

  char* ws = (char*)d_ws;
  u16*   Ah    = (u16*)(ws);                             // G_PAD*512 bf16
  u16*   Al    = (u16*)(ws + 20578304);
  u16*   Bh    = (u16*)(ws + 41156608);                  // 1536*512 bf16
  u16*   Bl    = (u16*)(ws + 42729472);
  float* tfT   = (float*)(ws + 44302336);                // [T, B] f32
  int*   tIdx  = (int*)(ws + 45875200);                  // [G, 32]
  float* tW    = (float*)(ws + 48435200);                // [G, 32]

  prep<<<11200, 256, 0, stream>>>(tg_dec, tf_base, tf_expr, Ah, Al, Bh, Bl, tfT);
  gemm_split<<<NWG, 512, 0, stream>>>(Ah, Al, Bh, Bl, attn);
  topk_kernel<<<5000, 256, 0, stream>>>(attn, motif_mask, tg_dec, tf_base, tIdx, tW);
  combine_kernel<<<1250, 256, 0, stream>>>(tfT, tIdx, tW, scale, out0);
}